// Round 18
// baseline (193.803 us; speedup 1.0000x reference)
//
#include <hip/hip_runtime.h>
#include <hip/hip_bf16.h>

#define EMBED 128
#define HEADS 16
#define NEG 0.2f

typedef __attribute__((ext_vector_type(8))) short short8;
typedef __attribute__((ext_vector_type(4))) float floatx4;

static __device__ __forceinline__ float leaky(float x) { return x > 0.f ? x : NEG * x; }

static __device__ __forceinline__ short f2bf_bits(float f) {
  __hip_bfloat16 h = __float2bfloat16(f);
  union { __hip_bfloat16 b; short s; } u;
  u.b = h;
  return u.s;
}

// ---------------- CSR build ----------------

__global__ void k_hist(const int* __restrict__ ei, int E, int N, int* __restrict__ deg) {
  int i = blockIdx.x * blockDim.x + threadIdx.x;
  int Et = E + N;
  if (i >= Et) return;
  int d = (i < E) ? ei[E + i] : (i - E);
  atomicAdd(&deg[d], 1);
}

__global__ __launch_bounds__(256) void k_scan1(const int* __restrict__ deg,
                                               int* __restrict__ excl,
                                               int* __restrict__ bsum, int n) {
  __shared__ int s[256];
  int i = blockIdx.x * 256 + threadIdx.x;
  int v = (i < n) ? deg[i] : 0;
  s[threadIdx.x] = v;
  __syncthreads();
  for (int d = 1; d < 256; d <<= 1) {
    int add = ((int)threadIdx.x >= d) ? s[threadIdx.x - d] : 0;
    __syncthreads();
    s[threadIdx.x] += add;
    __syncthreads();
  }
  if (i < n) excl[i] = s[threadIdx.x] - v;
  if (threadIdx.x == 255) bsum[blockIdx.x] = s[255];
}

__global__ void k_scan2(int* __restrict__ bsum, int nb) {
  if (threadIdx.x == 0 && blockIdx.x == 0) {
    int acc = 0;
    for (int i = 0; i < nb; ++i) { int v = bsum[i]; bsum[i] = acc; acc += v; }
  }
}

__global__ __launch_bounds__(256) void k_scan3(const int* __restrict__ deg,
                                               const int* __restrict__ excl,
                                               const int* __restrict__ bsum,
                                               int* __restrict__ row_ptr,
                                               int* __restrict__ cursor, int n) {
  int i = blockIdx.x * 256 + threadIdx.x;
  if (i < n) {
    int r = excl[i] + bsum[blockIdx.x];
    row_ptr[i] = r;
    cursor[i] = r;
    if (i == n - 1) row_ptr[n] = r + deg[i];
  }
}

__global__ void k_scatter(const int* __restrict__ ei, int E, int N,
                          int* __restrict__ cursor, int* __restrict__ csr_src) {
  int i = blockIdx.x * blockDim.x + threadIdx.x;
  int Et = E + N;
  if (i >= Et) return;
  int s = (i < E) ? ei[i] : (i - E);
  int d = (i < E) ? ei[E + i] : (i - E);
  int pos = atomicAdd(&cursor[d], 1);
  csr_src[pos] = s;
}

// ---------------- merged prep: w~ vectors (layer1 logits) + u vectors (layer2 folded) ----------------

__global__ __launch_bounds__(256) void k_prepAll(const float* __restrict__ W1,
                                                 const float* __restrict__ a_src1,
                                                 const float* __restrict__ a_dst1,
                                                 const float* __restrict__ W2,
                                                 const float* __restrict__ a_src2,
                                                 const float* __restrict__ a_dst2,
                                                 const float* __restrict__ Wc,
                                                 const float* __restrict__ b2,
                                                 const float* __restrict__ bc,
                                                 float* __restrict__ wsAll,
                                                 float* __restrict__ uvec,
                                                 float* __restrict__ cconst) {
  int gid = blockIdx.x * 256 + threadIdx.x;
  if (gid < 4096) {
    int sel = gid >> 11;
    int id = gid & 2047;
    int h = id >> 7, k = id & 127;
    const float* av = sel ? a_dst1 : a_src1;
    float sum = 0.f;
    const float* wrow = W1 + (size_t)k * 2048 + h * 128;
    const float* arow = av + h * 128;
#pragma unroll 4
    for (int c = 0; c < 128; ++c) sum += wrow[c] * arow[c];
    wsAll[gid] = sum;
  } else if (gid < 10240) {
    int g = gid - 4096;
    int sel = g >> 11;  // 0: Wc, 1: a_src2, 2: a_dst2
    int k = g & 2047;
    const float* v = sel == 0 ? Wc : (sel == 1 ? a_src2 : a_dst2);
    const float* wrow = W2 + (size_t)k * 128;
    float s = 0.f;
#pragma unroll 4
    for (int j = 0; j < 128; ++j) s += wrow[j] * v[j];
    uvec[g] = s;
  } else if (gid == 10240) {
    float s = 0.f;
    for (int j = 0; j < 128; ++j) s += b2[j] * Wc[j];
    *cconst = s + bc[0];
  }
}

// ---------------- W1^T hi/lo bf16 via LDS tile transpose: layout [h][j][c] ----------------

__global__ __launch_bounds__(256) void k_prep2aT(const float* __restrict__ W1,
                                                 short* __restrict__ hi,
                                                 short* __restrict__ lo) {
  __shared__ float tile[64][65];
  int h = blockIdx.x;
  int c0 = blockIdx.y * 64;
  int j0 = blockIdx.z * 64;
  int t = threadIdx.x;
#pragma unroll
  for (int i = 0; i < 4; ++i) {
    int idx4 = i * 256 + t;
    int c = idx4 >> 4, j4 = idx4 & 15;
    float4 v = *(const float4*)&W1[(size_t)(c0 + c) * 2048 + h * 128 + j0 + j4 * 4];
    tile[c][j4 * 4 + 0] = v.x;
    tile[c][j4 * 4 + 1] = v.y;
    tile[c][j4 * 4 + 2] = v.z;
    tile[c][j4 * 4 + 3] = v.w;
  }
  __syncthreads();
#pragma unroll
  for (int i = 0; i < 4; ++i) {
    int idx = i * 256 + t;
    int j = idx >> 4, c4 = idx & 15;
    unsigned short vh[4], vl[4];
#pragma unroll
    for (int ii = 0; ii < 4; ++ii) {
      float wv = tile[c4 * 4 + ii][j];
      short hb = f2bf_bits(wv);
      float hf = __uint_as_float(((unsigned int)(unsigned short)hb) << 16);
      vh[ii] = (unsigned short)hb;
      vl[ii] = (unsigned short)f2bf_bits(wv - hf);
    }
    size_t o = (size_t)h * 16384 + (size_t)(j0 + j) * 128 + c0 + c4 * 4;
    *(ushort4*)&hi[o] = make_ushort4(vh[0], vh[1], vh[2], vh[3]);
    *(ushort4*)&lo[o] = make_ushort4(vl[0], vl[1], vl[2], vl[3]);
  }
}

// ---------------- x -> bf16 copy (for the attn1 gather) ----------------

__global__ __launch_bounds__(256) void k_xbf(const float* __restrict__ x,
                                             __hip_bfloat16* __restrict__ xb, int N) {
  int gid = blockIdx.x * 256 + threadIdx.x;   // one uint4 (8 bf16) per thread
  if (gid >= N * 16) return;
  const float4* xp = (const float4*)(x) + gid * 2;
  float4 a = xp[0], b = xp[1];
  __hip_bfloat16 t[8];
  t[0] = __float2bfloat16(a.x); t[1] = __float2bfloat16(a.y);
  t[2] = __float2bfloat16(a.z); t[3] = __float2bfloat16(a.w);
  t[4] = __float2bfloat16(b.x); t[5] = __float2bfloat16(b.y);
  t[6] = __float2bfloat16(b.z); t[7] = __float2bfloat16(b.w);
  *(uint4*)(xb + (size_t)gid * 8) = *(uint4*)t;
}

// ---------------- layer-1 logits: thread per (n,h); weights [c][h] in LDS ----------------

__global__ __launch_bounds__(256) void k_al1v2(const float* __restrict__ x,
                                               const float* __restrict__ wsAll,
                                               float* __restrict__ als,
                                               float* __restrict__ ald, int N) {
  __shared__ float wss[128][16], wsd[128][16];
  int tid = threadIdx.x;
  for (int i = tid; i < 2048; i += 256) {
    int h = i >> 7, c = i & 127;
    wss[c][h] = wsAll[i];
    wsd[c][h] = wsAll[2048 + i];
  }
  __syncthreads();
  int gid = blockIdx.x * 256 + tid;
  int n = gid >> 4, h = gid & 15;
  if (n >= N) return;
  const float4* xp = (const float4*)(x + (size_t)n * 128);
  float ps = 0.f, pd = 0.f;
#pragma unroll 8
  for (int c4 = 0; c4 < 32; ++c4) {
    float4 xv = xp[c4];
    int c = c4 * 4;
    ps += xv.x * wss[c][h] + xv.y * wss[c + 1][h] + xv.z * wss[c + 2][h] + xv.w * wss[c + 3][h];
    pd += xv.x * wsd[c][h] + xv.y * wsd[c + 1][h] + xv.z * wsd[c + 2][h] + xv.w * wsd[c + 3][h];
  }
  als[gid] = ps;
  ald[gid] = pd;
}

// ---------------- layer-1 attention: attn1i — single pass, bf16 x gather (half the bytes) ----------------
// attn1h structure; per-edge x row read as one uint4 of 8 bf16 (16B/lane), unpacked in regs.

__global__ __launch_bounds__(256) void k_attn1i(const __hip_bfloat16* __restrict__ xb,
                                                const float* __restrict__ als,
                                                const float* __restrict__ ald,
                                                const int* __restrict__ row_ptr,
                                                const int* __restrict__ csr,
                                                __hip_bfloat16* __restrict__ xaggb,
                                                int N) {
  __shared__ float accsh[2][64][37];   // 32 acc + 4 z per lane

  int tid = threadIdx.x;
  int w = tid >> 6, lane = tid & 63;
  int slot = w >> 1, half = w & 1;
  int d = blockIdx.x * 2 + slot;
  bool active = d < N;

  int e0 = 0, deg = 0;
  if (active) {
    e0 = row_ptr[d];
    deg = row_ptr[d + 1] - e0;
  }

  int g = lane >> 4, c8 = lane & 15;
  float4 aldh4;
  if (active) aldh4 = *(const float4*)&ald[(size_t)d * 16 + g * 4];
  else aldh4 = make_float4(0.f, 0.f, 0.f, 0.f);

  float acc[4][8];
  float zacc[4] = {0.f, 0.f, 0.f, 0.f};
#pragma unroll
  for (int hh = 0; hh < 4; ++hh)
#pragma unroll
    for (int i = 0; i < 8; ++i) acc[hh][i] = 0.f;

  if (active) {
    const __hip_bfloat16* xc = xb + c8 * 8;
    for (int e = half; e < deg; e += 2) {
      int s = csr[e0 + e];
      float4 alv = *(const float4*)&als[(size_t)s * 16 + g * 4];
      uint4 u = *(const uint4*)(xc + (size_t)s * 128);
      float xv[8];
      xv[0] = __uint_as_float(u.x << 16);
      xv[1] = __uint_as_float(u.x & 0xffff0000u);
      xv[2] = __uint_as_float(u.y << 16);
      xv[3] = __uint_as_float(u.y & 0xffff0000u);
      xv[4] = __uint_as_float(u.z << 16);
      xv[5] = __uint_as_float(u.z & 0xffff0000u);
      xv[6] = __uint_as_float(u.w << 16);
      xv[7] = __uint_as_float(u.w & 0xffff0000u);
      float ev0 = __expf(leaky(alv.x + aldh4.x));
      float ev1 = __expf(leaky(alv.y + aldh4.y));
      float ev2 = __expf(leaky(alv.z + aldh4.z));
      float ev3 = __expf(leaky(alv.w + aldh4.w));
      zacc[0] += ev0; zacc[1] += ev1; zacc[2] += ev2; zacc[3] += ev3;
#pragma unroll
      for (int i = 0; i < 8; ++i) {
        acc[0][i] += ev0 * xv[i];
        acc[1][i] += ev1 * xv[i];
        acc[2][i] += ev2 * xv[i];
        acc[3][i] += ev3 * xv[i];
      }
    }
  }

  // combine halves through LDS (32 acc + 4 z per lane)
  if (half == 1) {
#pragma unroll
    for (int hh = 0; hh < 4; ++hh) {
#pragma unroll
      for (int i = 0; i < 8; ++i)
        accsh[slot][lane][hh * 8 + i] = acc[hh][i];
      accsh[slot][lane][32 + hh] = zacc[hh];
    }
  }
  __syncthreads();
  if (half == 0 && active) {
#pragma unroll
    for (int hh = 0; hh < 4; ++hh) {
      int h = g * 4 + hh;
      float z = zacc[hh] + accsh[slot][lane][32 + hh];
      float iz = 1.f / (z + 1e-16f);
      __hip_bfloat16 t[8];
#pragma unroll
      for (int i = 0; i < 8; ++i) {
        float v = (acc[hh][i] + accsh[slot][lane][hh * 8 + i]) * iz;
        t[i] = __float2bfloat16(v);
      }
      *(uint4*)(xaggb + (size_t)h * N * 128 + (size_t)d * 128 + c8 * 8) = *(uint4*)t;
    }
  }
}

// ---------------- fused v7: Bh+Bl in LDS, per-head coalesced partH stores (R15, best) ----------------

__global__ __launch_bounds__(256, 2) void k_fused(const __hip_bfloat16* __restrict__ xaggb,
                                                  const short* __restrict__ w1t_hi,
                                                  const short* __restrict__ w1t_lo,
                                                  const float* __restrict__ b1,
                                                  const float* __restrict__ uvec,
                                                  float* __restrict__ partH,
                                                  int N) {
  __shared__ float sh[512];
  __shared__ __align__(16) char Bh[32768];
  __shared__ __align__(16) char Bl[32768];
  int tid = threadIdx.x;
  int h = blockIdx.y;
  int n0 = blockIdx.x * 256;

  for (int i = tid; i < 512; i += 256) {
    int arr = i >> 7, jj = i & 127;
    sh[i] = (arr == 0) ? b1[h * 128 + jj] : uvec[(arr - 1) * 2048 + h * 128 + jj];
  }
  const char* gbh = (const char*)(w1t_hi + (size_t)h * 16384);
  const char* gbl = (const char*)(w1t_lo + (size_t)h * 16384);
#pragma unroll
  for (int i = 0; i < 8; ++i) {
    int ci = i * 256 + tid;
    int row = ci >> 4, kc = ci & 15;
    int po = row * 256 + ((kc ^ (row & 15)) << 4);
    *(uint4*)(Bh + po) = *(const uint4*)(gbh + ci * 16);
    *(uint4*)(Bl + po) = *(const uint4*)(gbl + ci * 16);
  }

  int w = tid >> 6, lane = tid & 63;
  int quad = lane >> 4, l15 = lane & 15;
  int nw = n0 + w * 64;

  const char* abase = (const char*)xaggb + (size_t)h * N * 256;
  short8 a[4][4];
#pragma unroll
  for (int nt = 0; nt < 4; ++nt) {
    int node = nw + nt * 16 + l15;
    if (node >= N) node = N - 1;
    const char* rowp = abase + (size_t)node * 256 + quad * 16;
#pragma unroll
    for (int ks = 0; ks < 4; ++ks)
      a[nt][ks] = *(const short8*)(rowp + ks * 64);
  }
  __syncthreads();

  floatx4 acc[4][8];
#pragma unroll
  for (int jt = 0; jt < 8; ++jt) {
    floatx4 bb = *(const floatx4*)&sh[jt * 16 + quad * 4];
#pragma unroll
    for (int nt = 0; nt < 4; ++nt) acc[nt][jt] = bb;
  }

  for (int ks = 0; ks < 4; ++ks) {
    int xo = (((ks * 4 + quad) ^ l15) << 4);
#pragma unroll
    for (int jt = 0; jt < 8; ++jt) {
      int po = (jt * 16 + l15) * 256 + xo;
      short8 wh = *(const short8*)(Bh + po);
      short8 wl = *(const short8*)(Bl + po);
#pragma unroll
      for (int nt = 0; nt < 4; ++nt) {
        acc[nt][jt] = __builtin_amdgcn_mfma_f32_16x16x32_bf16(wh, a[nt][ks], acc[nt][jt], 0, 0, 0);
        acc[nt][jt] = __builtin_amdgcn_mfma_f32_16x16x32_bf16(wl, a[nt][ks], acc[nt][jt], 0, 0, 0);
      }
    }
  }

  float pc[4] = {0.f, 0.f, 0.f, 0.f};
  float ps[4] = {0.f, 0.f, 0.f, 0.f};
  float pd[4] = {0.f, 0.f, 0.f, 0.f};
#pragma unroll
  for (int jt = 0; jt < 8; ++jt) {
    floatx4 uc = *(const floatx4*)&sh[128 + jt * 16 + quad * 4];
    floatx4 us = *(const floatx4*)&sh[256 + jt * 16 + quad * 4];
    floatx4 ud = *(const floatx4*)&sh[384 + jt * 16 + quad * 4];
#pragma unroll
    for (int nt = 0; nt < 4; ++nt) {
#pragma unroll
      for (int r = 0; r < 4; ++r) {
        float v = acc[nt][jt][r];
        float e = v > 0.f ? v : (__expf(v) - 1.f);
        pc[nt] += e * uc[r];
        ps[nt] += e * us[r];
        pd[nt] += e * ud[r];
      }
    }
  }
  float* pcH = partH + (size_t)h * N;
  float* psH = partH + (size_t)(16 + h) * N;
  float* pdH = partH + (size_t)(32 + h) * N;
#pragma unroll
  for (int nt = 0; nt < 4; ++nt) {
    float c = pc[nt], s = ps[nt], dd = pd[nt];
    c += __shfl_xor(c, 16); c += __shfl_xor(c, 32);
    s += __shfl_xor(s, 16); s += __shfl_xor(s, 32);
    dd += __shfl_xor(dd, 16); dd += __shfl_xor(dd, 32);
    int node = nw + nt * 16 + l15;
    if (quad == 0 && node < N) {
      pcH[node] = c;
      psH[node] = s;
      pdH[node] = dd;
    }
  }
}

// ---------------- sum per-head partials ----------------

__global__ __launch_bounds__(256) void k_redparts(const float* __restrict__ partH,
                                                  float* __restrict__ partc,
                                                  float* __restrict__ parts,
                                                  float* __restrict__ partd, int N) {
  int n = blockIdx.x * 256 + threadIdx.x;
  if (n >= N) return;
  float c = 0.f, s = 0.f, d = 0.f;
#pragma unroll
  for (int h = 0; h < 16; ++h) {
    c += partH[(size_t)h * N + n];
    s += partH[(size_t)(16 + h) * N + n];
    d += partH[(size_t)(32 + h) * N + n];
  }
  partc[n] = c;
  parts[n] = s;
  partd[n] = d;
}

// ---------------- layer-2 attention, all-scalar, single pass (no max) ----------------

__global__ __launch_bounds__(256) void k_attn2s(const float* __restrict__ partc,
                                                const float* __restrict__ parts,
                                                const float* __restrict__ partd,
                                                const int* __restrict__ row_ptr,
                                                const int* __restrict__ csr,
                                                const float* __restrict__ cconst,
                                                float* __restrict__ out, int N) {
  int w = threadIdx.x >> 6, lane = threadIdx.x & 63;
  int d = blockIdx.x * 4 + w;
  if (d >= N) return;
  int e0 = row_ptr[d], deg = row_ptr[d + 1] - e0;
  float aldd = partd[d];
  float z = 0.f, num = 0.f;
  for (int e = lane; e < deg; e += 64) {
    int s = csr[e0 + e];
    float v = __expf(leaky(parts[s] + aldd));
    z += v;
    num += v * partc[s];
  }
#pragma unroll
  for (int off = 32; off; off >>= 1) {
    z += __shfl_xor(z, off);
    num += __shfl_xor(num, off);
  }
  if (lane == 0) out[d] = num / (z + 1e-16f) + cconst[0];
}

// ---------------- launch ----------------

extern "C" void kernel_launch(void* const* d_in, const int* in_sizes, int n_in,
                              void* d_out, int out_size, void* d_ws, size_t ws_size,
                              hipStream_t stream) {
  const float* x      = (const float*)d_in[0];
  const int*   ei     = (const int*)d_in[1];
  const float* W1     = (const float*)d_in[2];
  const float* a_src1 = (const float*)d_in[3];
  const float* a_dst1 = (const float*)d_in[4];
  const float* b1     = (const float*)d_in[5];
  const float* W2     = (const float*)d_in[6];
  const float* a_src2 = (const float*)d_in[7];
  const float* a_dst2 = (const float*)d_in[8];
  const float* b2     = (const float*)d_in[9];
  const float* Wc     = (const float*)d_in[10];
  const float* bc     = (const float*)d_in[11];

  int N = in_sizes[0] / EMBED;
  int E = in_sizes[1] / 2;
  int Et = E + N;
  int nScanB = (N + 255) / 256;

  char* ws = (char*)d_ws;
  size_t off = 0;
  auto alloc = [&](size_t bytes) -> void* {
    void* p = ws + off;
    off += (bytes + 255) & ~(size_t)255;
    return p;
  };
  __hip_bfloat16* xaggb = (__hip_bfloat16*)alloc((size_t)N * 2048 * 2 + 65536);
  __hip_bfloat16* xb    = (__hip_bfloat16*)alloc((size_t)N * 128 * 2);
  short* w1t_hi = (short*)alloc((size_t)262144 * 2);
  short* w1t_lo = (short*)alloc((size_t)262144 * 2);
  float* wsAll  = (float*)alloc(4096 * 4);
  float* uvec   = (float*)alloc(6144 * 4);
  float* cconst = (float*)alloc(256);
  float* als1   = (float*)alloc((size_t)N * 16 * 4);
  float* ald1   = (float*)alloc((size_t)N * 16 * 4);
  float* partH  = (float*)alloc((size_t)48 * N * 4);
  float* part   = (float*)alloc((size_t)3 * N * 4);
  float* partc  = part;
  float* parts  = part + N;
  float* partd  = part + 2 * N;
  int* deg      = (int*)alloc((size_t)N * 4);
  int* excl     = (int*)alloc((size_t)N * 4);
  int* bsum     = (int*)alloc((size_t)(nScanB + 1) * 4);
  int* row_ptr  = (int*)alloc((size_t)(N + 1) * 4);
  int* cursor   = (int*)alloc((size_t)N * 4);
  int* csr      = (int*)alloc((size_t)Et * 4);

  hipMemsetAsync(deg, 0, (size_t)N * 4, stream);

  k_hist<<<(Et + 255) / 256, 256, 0, stream>>>(ei, E, N, deg);
  k_scan1<<<nScanB, 256, 0, stream>>>(deg, excl, bsum, N);
  k_scan2<<<1, 64, 0, stream>>>(bsum, nScanB);
  k_scan3<<<nScanB, 256, 0, stream>>>(deg, excl, bsum, row_ptr, cursor, N);
  k_scatter<<<(Et + 255) / 256, 256, 0, stream>>>(ei, E, N, cursor, csr);

  k_prepAll<<<41, 256, 0, stream>>>(W1, a_src1, a_dst1, W2, a_src2, a_dst2, Wc, b2, bc,
                                    wsAll, uvec, cconst);
  k_prep2aT<<<dim3(16, 2, 2), 256, 0, stream>>>(W1, w1t_hi, w1t_lo);
  k_xbf<<<(N * 16 + 255) / 256, 256, 0, stream>>>(x, xb, N);

  k_al1v2<<<(N * 16 + 255) / 256, 256, 0, stream>>>(x, wsAll, als1, ald1, N);
  k_attn1i<<<(N + 1) / 2, 256, 0, stream>>>(xb, als1, ald1, row_ptr, csr, xaggb, N);

  k_fused<<<dim3((N + 255) / 256, 16), 256, 0, stream>>>(xaggb, w1t_hi, w1t_lo, b1, uvec,
                                                         partH, N);
  k_redparts<<<(N + 255) / 256, 256, 0, stream>>>(partH, partc, parts, partd, N);
  k_attn2s<<<(N + 3) / 4, 256, 0, stream>>>(partc, parts, partd, row_ptr, csr, cconst,
                                            (float*)d_out, N);
}

// Round 19
// 190.373 us; speedup vs baseline: 1.0180x; 1.0180x over previous
//
#include <hip/hip_runtime.h>
#include <hip/hip_bf16.h>

#define EMBED 128
#define HEADS 16
#define NEG 0.2f

typedef __attribute__((ext_vector_type(8))) short short8;
typedef __attribute__((ext_vector_type(4))) float floatx4;

static __device__ __forceinline__ float leaky(float x) { return x > 0.f ? x : NEG * x; }

static __device__ __forceinline__ short f2bf_bits(float f) {
  __hip_bfloat16 h = __float2bfloat16(f);
  union { __hip_bfloat16 b; short s; } u;
  u.b = h;
  return u.s;
}

// ---------------- CSR build ----------------

__global__ void k_hist(const int* __restrict__ ei, int E, int N, int* __restrict__ deg) {
  int i = blockIdx.x * blockDim.x + threadIdx.x;
  int Et = E + N;
  if (i >= Et) return;
  int d = (i < E) ? ei[E + i] : (i - E);
  atomicAdd(&deg[d], 1);
}

__global__ __launch_bounds__(256) void k_scan1(const int* __restrict__ deg,
                                               int* __restrict__ excl,
                                               int* __restrict__ bsum, int n) {
  __shared__ int s[256];
  int i = blockIdx.x * 256 + threadIdx.x;
  int v = (i < n) ? deg[i] : 0;
  s[threadIdx.x] = v;
  __syncthreads();
  for (int d = 1; d < 256; d <<= 1) {
    int add = ((int)threadIdx.x >= d) ? s[threadIdx.x - d] : 0;
    __syncthreads();
    s[threadIdx.x] += add;
    __syncthreads();
  }
  if (i < n) excl[i] = s[threadIdx.x] - v;
  if (threadIdx.x == 255) bsum[blockIdx.x] = s[255];
}

__global__ void k_scan2(int* __restrict__ bsum, int nb) {
  if (threadIdx.x == 0 && blockIdx.x == 0) {
    int acc = 0;
    for (int i = 0; i < nb; ++i) { int v = bsum[i]; bsum[i] = acc; acc += v; }
  }
}

__global__ __launch_bounds__(256) void k_scan3(const int* __restrict__ deg,
                                               const int* __restrict__ excl,
                                               const int* __restrict__ bsum,
                                               int* __restrict__ row_ptr,
                                               int* __restrict__ cursor, int n) {
  int i = blockIdx.x * 256 + threadIdx.x;
  if (i < n) {
    int r = excl[i] + bsum[blockIdx.x];
    row_ptr[i] = r;
    cursor[i] = r;
    if (i == n - 1) row_ptr[n] = r + deg[i];
  }
}

__global__ void k_scatter(const int* __restrict__ ei, int E, int N,
                          int* __restrict__ cursor, int* __restrict__ csr_src) {
  int i = blockIdx.x * blockDim.x + threadIdx.x;
  int Et = E + N;
  if (i >= Et) return;
  int s = (i < E) ? ei[i] : (i - E);
  int d = (i < E) ? ei[E + i] : (i - E);
  int pos = atomicAdd(&cursor[d], 1);
  csr_src[pos] = s;
}

// ---------------- merged prep: w~ vectors (layer1 logits) + u vectors (layer2 folded) ----------------

__global__ __launch_bounds__(256) void k_prepAll(const float* __restrict__ W1,
                                                 const float* __restrict__ a_src1,
                                                 const float* __restrict__ a_dst1,
                                                 const float* __restrict__ W2,
                                                 const float* __restrict__ a_src2,
                                                 const float* __restrict__ a_dst2,
                                                 const float* __restrict__ Wc,
                                                 const float* __restrict__ b2,
                                                 const float* __restrict__ bc,
                                                 float* __restrict__ wsAll,
                                                 float* __restrict__ uvec,
                                                 float* __restrict__ cconst) {
  int gid = blockIdx.x * 256 + threadIdx.x;
  if (gid < 4096) {
    int sel = gid >> 11;
    int id = gid & 2047;
    int h = id >> 7, k = id & 127;
    const float* av = sel ? a_dst1 : a_src1;
    float sum = 0.f;
    const float* wrow = W1 + (size_t)k * 2048 + h * 128;
    const float* arow = av + h * 128;
#pragma unroll 4
    for (int c = 0; c < 128; ++c) sum += wrow[c] * arow[c];
    wsAll[gid] = sum;
  } else if (gid < 10240) {
    int g = gid - 4096;
    int sel = g >> 11;  // 0: Wc, 1: a_src2, 2: a_dst2
    int k = g & 2047;
    const float* v = sel == 0 ? Wc : (sel == 1 ? a_src2 : a_dst2);
    const float* wrow = W2 + (size_t)k * 128;
    float s = 0.f;
#pragma unroll 4
    for (int j = 0; j < 128; ++j) s += wrow[j] * v[j];
    uvec[g] = s;
  } else if (gid == 10240) {
    float s = 0.f;
    for (int j = 0; j < 128; ++j) s += b2[j] * Wc[j];
    *cconst = s + bc[0];
  }
}

// ---------------- W1^T hi/lo bf16 via LDS tile transpose: layout [h][j][c] ----------------

__global__ __launch_bounds__(256) void k_prep2aT(const float* __restrict__ W1,
                                                 short* __restrict__ hi,
                                                 short* __restrict__ lo) {
  __shared__ float tile[64][65];
  int h = blockIdx.x;
  int c0 = blockIdx.y * 64;
  int j0 = blockIdx.z * 64;
  int t = threadIdx.x;
#pragma unroll
  for (int i = 0; i < 4; ++i) {
    int idx4 = i * 256 + t;
    int c = idx4 >> 4, j4 = idx4 & 15;
    float4 v = *(const float4*)&W1[(size_t)(c0 + c) * 2048 + h * 128 + j0 + j4 * 4];
    tile[c][j4 * 4 + 0] = v.x;
    tile[c][j4 * 4 + 1] = v.y;
    tile[c][j4 * 4 + 2] = v.z;
    tile[c][j4 * 4 + 3] = v.w;
  }
  __syncthreads();
#pragma unroll
  for (int i = 0; i < 4; ++i) {
    int idx = i * 256 + t;
    int j = idx >> 4, c4 = idx & 15;
    unsigned short vh[4], vl[4];
#pragma unroll
    for (int ii = 0; ii < 4; ++ii) {
      float wv = tile[c4 * 4 + ii][j];
      short hb = f2bf_bits(wv);
      float hf = __uint_as_float(((unsigned int)(unsigned short)hb) << 16);
      vh[ii] = (unsigned short)hb;
      vl[ii] = (unsigned short)f2bf_bits(wv - hf);
    }
    size_t o = (size_t)h * 16384 + (size_t)(j0 + j) * 128 + c0 + c4 * 4;
    *(ushort4*)&hi[o] = make_ushort4(vh[0], vh[1], vh[2], vh[3]);
    *(ushort4*)&lo[o] = make_ushort4(vl[0], vl[1], vl[2], vl[3]);
  }
}

// ---------------- layer-1 logits: thread per (n,h); weights [c][h] in LDS ----------------

__global__ __launch_bounds__(256) void k_al1v2(const float* __restrict__ x,
                                               const float* __restrict__ wsAll,
                                               float* __restrict__ als,
                                               float* __restrict__ ald, int N) {
  __shared__ float wss[128][16], wsd[128][16];
  int tid = threadIdx.x;
  for (int i = tid; i < 2048; i += 256) {
    int h = i >> 7, c = i & 127;
    wss[c][h] = wsAll[i];
    wsd[c][h] = wsAll[2048 + i];
  }
  __syncthreads();
  int gid = blockIdx.x * 256 + tid;
  int n = gid >> 4, h = gid & 15;
  if (n >= N) return;
  const float4* xp = (const float4*)(x + (size_t)n * 128);
  float ps = 0.f, pd = 0.f;
#pragma unroll 8
  for (int c4 = 0; c4 < 32; ++c4) {
    float4 xv = xp[c4];
    int c = c4 * 4;
    ps += xv.x * wss[c][h] + xv.y * wss[c + 1][h] + xv.z * wss[c + 2][h] + xv.w * wss[c + 3][h];
    pd += xv.x * wsd[c][h] + xv.y * wsd[c + 1][h] + xv.z * wsd[c + 2][h] + xv.w * wsd[c + 3][h];
  }
  als[gid] = ps;
  ald[gid] = pd;
}

// ---------------- layer-1 attention: attn1h — SINGLE edge pass, z fused into aggregation ----------------

__global__ __launch_bounds__(256) void k_attn1h(const float* __restrict__ x,
                                                const float* __restrict__ als,
                                                const float* __restrict__ ald,
                                                const int* __restrict__ row_ptr,
                                                const int* __restrict__ csr,
                                                __hip_bfloat16* __restrict__ xaggb,
                                                int N) {
  __shared__ float accsh[2][64][37];   // 32 acc + 4 z per lane

  int tid = threadIdx.x;
  int w = tid >> 6, lane = tid & 63;
  int slot = w >> 1, half = w & 1;
  int d = blockIdx.x * 2 + slot;
  bool active = d < N;

  int e0 = 0, deg = 0;
  if (active) {
    e0 = row_ptr[d];
    deg = row_ptr[d + 1] - e0;
  }

  int g = lane >> 4, c8 = lane & 15;
  float4 aldh4;
  if (active) aldh4 = *(const float4*)&ald[(size_t)d * 16 + g * 4];
  else aldh4 = make_float4(0.f, 0.f, 0.f, 0.f);

  float acc[4][8];
  float zacc[4] = {0.f, 0.f, 0.f, 0.f};
#pragma unroll
  for (int hh = 0; hh < 4; ++hh)
#pragma unroll
    for (int i = 0; i < 8; ++i) acc[hh][i] = 0.f;

  if (active) {
    const float* xc = x + c8 * 8;
    for (int e = half; e < deg; e += 2) {
      int s = csr[e0 + e];
      float4 alv = *(const float4*)&als[(size_t)s * 16 + g * 4];
      const float4* xp = (const float4*)(xc + (size_t)s * 128);
      float4 xa = xp[0], xb = xp[1];
      float ev0 = __expf(leaky(alv.x + aldh4.x));
      float ev1 = __expf(leaky(alv.y + aldh4.y));
      float ev2 = __expf(leaky(alv.z + aldh4.z));
      float ev3 = __expf(leaky(alv.w + aldh4.w));
      zacc[0] += ev0; zacc[1] += ev1; zacc[2] += ev2; zacc[3] += ev3;
      acc[0][0] += ev0 * xa.x; acc[0][1] += ev0 * xa.y; acc[0][2] += ev0 * xa.z; acc[0][3] += ev0 * xa.w;
      acc[0][4] += ev0 * xb.x; acc[0][5] += ev0 * xb.y; acc[0][6] += ev0 * xb.z; acc[0][7] += ev0 * xb.w;
      acc[1][0] += ev1 * xa.x; acc[1][1] += ev1 * xa.y; acc[1][2] += ev1 * xa.z; acc[1][3] += ev1 * xa.w;
      acc[1][4] += ev1 * xb.x; acc[1][5] += ev1 * xb.y; acc[1][6] += ev1 * xb.z; acc[1][7] += ev1 * xb.w;
      acc[2][0] += ev2 * xa.x; acc[2][1] += ev2 * xa.y; acc[2][2] += ev2 * xa.z; acc[2][3] += ev2 * xa.w;
      acc[2][4] += ev2 * xb.x; acc[2][5] += ev2 * xb.y; acc[2][6] += ev2 * xb.z; acc[2][7] += ev2 * xb.w;
      acc[3][0] += ev3 * xa.x; acc[3][1] += ev3 * xa.y; acc[3][2] += ev3 * xa.z; acc[3][3] += ev3 * xa.w;
      acc[3][4] += ev3 * xb.x; acc[3][5] += ev3 * xb.y; acc[3][6] += ev3 * xb.z; acc[3][7] += ev3 * xb.w;
    }
  }

  // combine halves through LDS (32 acc + 4 z per lane)
  if (half == 1) {
#pragma unroll
    for (int hh = 0; hh < 4; ++hh) {
#pragma unroll
      for (int i = 0; i < 8; ++i)
        accsh[slot][lane][hh * 8 + i] = acc[hh][i];
      accsh[slot][lane][32 + hh] = zacc[hh];
    }
  }
  __syncthreads();
  if (half == 0 && active) {
#pragma unroll
    for (int hh = 0; hh < 4; ++hh) {
      int h = g * 4 + hh;
      float z = zacc[hh] + accsh[slot][lane][32 + hh];
      float iz = 1.f / (z + 1e-16f);
      __hip_bfloat16 t[8];
#pragma unroll
      for (int i = 0; i < 8; ++i) {
        float v = (acc[hh][i] + accsh[slot][lane][hh * 8 + i]) * iz;
        t[i] = __float2bfloat16(v);
      }
      *(uint4*)(xaggb + (size_t)h * N * 128 + (size_t)d * 128 + c8 * 8) = *(uint4*)t;
    }
  }
}

// ---------------- fused v7: Bh+Bl in LDS, per-head coalesced partH stores ----------------

__global__ __launch_bounds__(256, 2) void k_fused(const __hip_bfloat16* __restrict__ xaggb,
                                                  const short* __restrict__ w1t_hi,
                                                  const short* __restrict__ w1t_lo,
                                                  const float* __restrict__ b1,
                                                  const float* __restrict__ uvec,
                                                  float* __restrict__ partH,
                                                  int N) {
  __shared__ float sh[512];
  __shared__ __align__(16) char Bh[32768];
  __shared__ __align__(16) char Bl[32768];
  int tid = threadIdx.x;
  int h = blockIdx.y;
  int n0 = blockIdx.x * 256;

  for (int i = tid; i < 512; i += 256) {
    int arr = i >> 7, jj = i & 127;
    sh[i] = (arr == 0) ? b1[h * 128 + jj] : uvec[(arr - 1) * 2048 + h * 128 + jj];
  }
  const char* gbh = (const char*)(w1t_hi + (size_t)h * 16384);
  const char* gbl = (const char*)(w1t_lo + (size_t)h * 16384);
#pragma unroll
  for (int i = 0; i < 8; ++i) {
    int ci = i * 256 + tid;
    int row = ci >> 4, kc = ci & 15;
    int po = row * 256 + ((kc ^ (row & 15)) << 4);
    *(uint4*)(Bh + po) = *(const uint4*)(gbh + ci * 16);
    *(uint4*)(Bl + po) = *(const uint4*)(gbl + ci * 16);
  }

  int w = tid >> 6, lane = tid & 63;
  int quad = lane >> 4, l15 = lane & 15;
  int nw = n0 + w * 64;

  const char* abase = (const char*)xaggb + (size_t)h * N * 256;
  short8 a[4][4];
#pragma unroll
  for (int nt = 0; nt < 4; ++nt) {
    int node = nw + nt * 16 + l15;
    if (node >= N) node = N - 1;
    const char* rowp = abase + (size_t)node * 256 + quad * 16;
#pragma unroll
    for (int ks = 0; ks < 4; ++ks)
      a[nt][ks] = *(const short8*)(rowp + ks * 64);
  }
  __syncthreads();

  floatx4 acc[4][8];
#pragma unroll
  for (int jt = 0; jt < 8; ++jt) {
    floatx4 bb = *(const floatx4*)&sh[jt * 16 + quad * 4];
#pragma unroll
    for (int nt = 0; nt < 4; ++nt) acc[nt][jt] = bb;
  }

  for (int ks = 0; ks < 4; ++ks) {
    int xo = (((ks * 4 + quad) ^ l15) << 4);
#pragma unroll
    for (int jt = 0; jt < 8; ++jt) {
      int po = (jt * 16 + l15) * 256 + xo;
      short8 wh = *(const short8*)(Bh + po);
      short8 wl = *(const short8*)(Bl + po);
#pragma unroll
      for (int nt = 0; nt < 4; ++nt) {
        acc[nt][jt] = __builtin_amdgcn_mfma_f32_16x16x32_bf16(wh, a[nt][ks], acc[nt][jt], 0, 0, 0);
        acc[nt][jt] = __builtin_amdgcn_mfma_f32_16x16x32_bf16(wl, a[nt][ks], acc[nt][jt], 0, 0, 0);
      }
    }
  }

  float pc[4] = {0.f, 0.f, 0.f, 0.f};
  float ps[4] = {0.f, 0.f, 0.f, 0.f};
  float pd[4] = {0.f, 0.f, 0.f, 0.f};
#pragma unroll
  for (int jt = 0; jt < 8; ++jt) {
    floatx4 uc = *(const floatx4*)&sh[128 + jt * 16 + quad * 4];
    floatx4 us = *(const floatx4*)&sh[256 + jt * 16 + quad * 4];
    floatx4 ud = *(const floatx4*)&sh[384 + jt * 16 + quad * 4];
#pragma unroll
    for (int nt = 0; nt < 4; ++nt) {
#pragma unroll
      for (int r = 0; r < 4; ++r) {
        float v = acc[nt][jt][r];
        float e = v > 0.f ? v : (__expf(v) - 1.f);
        pc[nt] += e * uc[r];
        ps[nt] += e * us[r];
        pd[nt] += e * ud[r];
      }
    }
  }
  float* pcH = partH + (size_t)h * N;
  float* psH = partH + (size_t)(16 + h) * N;
  float* pdH = partH + (size_t)(32 + h) * N;
#pragma unroll
  for (int nt = 0; nt < 4; ++nt) {
    float c = pc[nt], s = ps[nt], dd = pd[nt];
    c += __shfl_xor(c, 16); c += __shfl_xor(c, 32);
    s += __shfl_xor(s, 16); s += __shfl_xor(s, 32);
    dd += __shfl_xor(dd, 16); dd += __shfl_xor(dd, 32);
    int node = nw + nt * 16 + l15;
    if (quad == 0 && node < N) {
      pcH[node] = c;
      psH[node] = s;
      pdH[node] = dd;
    }
  }
}

// ---------------- sum per-head partials ----------------

__global__ __launch_bounds__(256) void k_redparts(const float* __restrict__ partH,
                                                  float* __restrict__ partc,
                                                  float* __restrict__ parts,
                                                  float* __restrict__ partd, int N) {
  int n = blockIdx.x * 256 + threadIdx.x;
  if (n >= N) return;
  float c = 0.f, s = 0.f, d = 0.f;
#pragma unroll
  for (int h = 0; h < 16; ++h) {
    c += partH[(size_t)h * N + n];
    s += partH[(size_t)(16 + h) * N + n];
    d += partH[(size_t)(32 + h) * N + n];
  }
  partc[n] = c;
  parts[n] = s;
  partd[n] = d;
}

// ---------------- layer-2 attention, all-scalar, single pass (no max) ----------------

__global__ __launch_bounds__(256) void k_attn2s(const float* __restrict__ partc,
                                                const float* __restrict__ parts,
                                                const float* __restrict__ partd,
                                                const int* __restrict__ row_ptr,
                                                const int* __restrict__ csr,
                                                const float* __restrict__ cconst,
                                                float* __restrict__ out, int N) {
  int w = threadIdx.x >> 6, lane = threadIdx.x & 63;
  int d = blockIdx.x * 4 + w;
  if (d >= N) return;
  int e0 = row_ptr[d], deg = row_ptr[d + 1] - e0;
  float aldd = partd[d];
  float z = 0.f, num = 0.f;
  for (int e = lane; e < deg; e += 64) {
    int s = csr[e0 + e];
    float v = __expf(leaky(parts[s] + aldd));
    z += v;
    num += v * partc[s];
  }
#pragma unroll
  for (int off = 32; off; off >>= 1) {
    z += __shfl_xor(z, off);
    num += __shfl_xor(num, off);
  }
  if (lane == 0) out[d] = num / (z + 1e-16f) + cconst[0];
}

// ---------------- launch ----------------

extern "C" void kernel_launch(void* const* d_in, const int* in_sizes, int n_in,
                              void* d_out, int out_size, void* d_ws, size_t ws_size,
                              hipStream_t stream) {
  const float* x      = (const float*)d_in[0];
  const int*   ei     = (const int*)d_in[1];
  const float* W1     = (const float*)d_in[2];
  const float* a_src1 = (const float*)d_in[3];
  const float* a_dst1 = (const float*)d_in[4];
  const float* b1     = (const float*)d_in[5];
  const float* W2     = (const float*)d_in[6];
  const float* a_src2 = (const float*)d_in[7];
  const float* a_dst2 = (const float*)d_in[8];
  const float* b2     = (const float*)d_in[9];
  const float* Wc     = (const float*)d_in[10];
  const float* bc     = (const float*)d_in[11];

  int N = in_sizes[0] / EMBED;
  int E = in_sizes[1] / 2;
  int Et = E + N;
  int nScanB = (N + 255) / 256;

  char* ws = (char*)d_ws;
  size_t off = 0;
  auto alloc = [&](size_t bytes) -> void* {
    void* p = ws + off;
    off += (bytes + 255) & ~(size_t)255;
    return p;
  };
  __hip_bfloat16* xaggb = (__hip_bfloat16*)alloc((size_t)N * 2048 * 2 + 65536);
  short* w1t_hi = (short*)alloc((size_t)262144 * 2);
  short* w1t_lo = (short*)alloc((size_t)262144 * 2);
  float* wsAll  = (float*)alloc(4096 * 4);
  float* uvec   = (float*)alloc(6144 * 4);
  float* cconst = (float*)alloc(256);
  float* als1   = (float*)alloc((size_t)N * 16 * 4);
  float* ald1   = (float*)alloc((size_t)N * 16 * 4);
  float* partH  = (float*)alloc((size_t)48 * N * 4);
  float* part   = (float*)alloc((size_t)3 * N * 4);
  float* partc  = part;
  float* parts  = part + N;
  float* partd  = part + 2 * N;
  int* deg      = (int*)alloc((size_t)N * 4);
  int* excl     = (int*)alloc((size_t)N * 4);
  int* bsum     = (int*)alloc((size_t)(nScanB + 1) * 4);
  int* row_ptr  = (int*)alloc((size_t)(N + 1) * 4);
  int* cursor   = (int*)alloc((size_t)N * 4);
  int* csr      = (int*)alloc((size_t)Et * 4);

  hipMemsetAsync(deg, 0, (size_t)N * 4, stream);

  k_hist<<<(Et + 255) / 256, 256, 0, stream>>>(ei, E, N, deg);
  k_scan1<<<nScanB, 256, 0, stream>>>(deg, excl, bsum, N);
  k_scan2<<<1, 64, 0, stream>>>(bsum, nScanB);
  k_scan3<<<nScanB, 256, 0, stream>>>(deg, excl, bsum, row_ptr, cursor, N);
  k_scatter<<<(Et + 255) / 256, 256, 0, stream>>>(ei, E, N, cursor, csr);

  k_prepAll<<<41, 256, 0, stream>>>(W1, a_src1, a_dst1, W2, a_src2, a_dst2, Wc, b2, bc,
                                    wsAll, uvec, cconst);
  k_prep2aT<<<dim3(16, 2, 2), 256, 0, stream>>>(W1, w1t_hi, w1t_lo);

  k_al1v2<<<(N * 16 + 255) / 256, 256, 0, stream>>>(x, wsAll, als1, ald1, N);
  k_attn1h<<<(N + 1) / 2, 256, 0, stream>>>(x, als1, ald1, row_ptr, csr, xaggb, N);

  k_fused<<<dim3((N + 255) / 256, 16), 256, 0, stream>>>(xaggb, w1t_hi, w1t_lo, b1, uvec,
                                                         partH, N);
  k_redparts<<<(N + 255) / 256, 256, 0, stream>>>(partH, partc, parts, partd, N);
  k_attn2s<<<(N + 3) / 4, 256, 0, stream>>>(partc, parts, partd, row_ptr, csr, cconst,
                                            (float*)d_out, N);
}